// Round 5
// baseline (920.071 us; speedup 1.0000x reference)
//
#include <hip/hip_runtime.h>
#include <cstdint>
#include <cstddef>

#define EPSF 1e-6f

static constexpr int Bc  = 4;
static constexpr int Nc  = 4096;
static constexpr int Cch = 1024;
static constexpr int Hc  = 16;
static constexpr int Dc  = 64;
static constexpr int BHc = Bc * Hc;                      // 64
static constexpr size_t HEADSZ = (size_t)BHc * Nc * Dc;  // 16,777,216 floats
static constexpr int Kd  = 1024;                         // inner dim of both GEMMs

typedef __attribute__((ext_vector_type(8))) short     s16x8;
typedef __attribute__((ext_vector_type(4))) float     f32x4;

__device__ __forceinline__ float sigmoid_f(float x) {
  return 1.0f / (1.0f + __expf(-x));
}

// ---- bf16 helpers ---------------------------------------------------------
__device__ __forceinline__ unsigned short bf16_rne(float x) {
  unsigned int b = __float_as_uint(x);
  b += 0x7fffu + ((b >> 16) & 1u);
  return (unsigned short)(b >> 16);
}
__device__ __forceinline__ float bf16_to_f(unsigned short u) {
  return __uint_as_float(((unsigned int)u) << 16);
}
// truncating split: x = hi + lo + O(2^-16 |x|); hi/lo both bf16
__device__ __forceinline__ void split_trunc(float x, unsigned short& h, unsigned short& l) {
  unsigned int b  = __float_as_uint(x);
  unsigned int hb = b & 0xffff0000u;
  h = (unsigned short)(hb >> 16);
  float res = x - __uint_as_float(hb);
  l = (unsigned short)(__float_as_uint(res) >> 16);
}

// async global->LDS, 16B per lane; LDS dest = wave-uniform base + lane*16
__device__ __forceinline__ void gl_lds16(const unsigned short* g, unsigned short* l) {
  __builtin_amdgcn_global_load_lds(
      (const __attribute__((address_space(1))) unsigned int*)(const void*)g,
      (__attribute__((address_space(3))) unsigned int*)(void*)l,
      16, 0, 0);
}

// ---------------------------------------------------------------------------
// fp32 -> (hi, lo) bf16 split, RNE both.  n4 = nelems/4.
// ---------------------------------------------------------------------------
__global__ __launch_bounds__(256)
void split_kernel(const float* __restrict__ in, unsigned short* __restrict__ hi,
                  unsigned short* __restrict__ lo, int n4)
{
  int i = blockIdx.x * 256 + threadIdx.x;
  if (i >= n4) return;
  float4 v = ((const float4*)in)[i];
  ushort4 h, l;
  h.x = bf16_rne(v.x); l.x = bf16_rne(v.x - bf16_to_f(h.x));
  h.y = bf16_rne(v.y); l.y = bf16_rne(v.y - bf16_to_f(h.y));
  h.z = bf16_rne(v.z); l.z = bf16_rne(v.z - bf16_to_f(h.z));
  h.w = bf16_rne(v.w); l.w = bf16_rne(v.w - bf16_to_f(h.w));
  ((ushort4*)hi)[i] = h;
  ((ushort4*)lo)[i] = l;
}

// ---------------------------------------------------------------------------
// bf16x3 MFMA GEMM (TN): out[m][r] = sum_c A[m][c]*W[r][c] + bias[r]
// A and W both pre-split bf16 hi/lo; ALL staging via global_load_lds width=16
// (m97 structure: 2 barriers/K-step, no staging VALU in the hot loop).
// MODE 0: N=3072, scatter q/k/v head-major + sigmoid(q,k) + fused q/k sums.
// MODE 1: N=1024, plain fp32 row-major store.
// Block: 256 thr = 4 waves (2x2), tile 128x128x32, wave tile 64x64 = 4x4 frags
// of v_mfma_f32_16x16x32_bf16; 3 MFMAs per frag pair (hh + hl + lh).
// XCD-bijective block swizzle (grid sizes divisible by 8).
// ---------------------------------------------------------------------------
template <int MODE>
__global__ __launch_bounds__(256)
void gemm_mfma(const unsigned short* __restrict__ Ah_g, const unsigned short* __restrict__ Al_g,
               const unsigned short* __restrict__ Wh_g, const unsigned short* __restrict__ Wl_g,
               const float* __restrict__ bias,
               float* __restrict__ out0, float* __restrict__ out1, float* __restrict__ out2,
               float* __restrict__ qsum_g, float* __restrict__ ksum_g)
{
  __shared__ unsigned short Ahs[128][32];
  __shared__ unsigned short Als[128][32];
  __shared__ unsigned short Whs[128][32];
  __shared__ unsigned short Wls[128][32];

  // XCD-aware bijective swizzle: nwg % 8 == 0 for both grids.
  const int gx  = gridDim.x;
  const int nwg = gx * gridDim.y;
  const int bid = blockIdx.y * gx + blockIdx.x;
  const int swz = (bid & 7) * (nwg >> 3) + (bid >> 3);
  const int bx  = swz % gx;
  const int by  = swz / gx;

  const int t    = threadIdx.x;
  const int lane = t & 63;
  const int wid  = t >> 6;
  const int wr   = wid >> 1, wc = wid & 1;
  const int r16  = lane & 15, g = lane >> 4;
  const int m0   = bx * 128;
  const int r0   = by * 128;

  // DMA staging geometry: wave wid covers rows [wid*32, wid*32+32), two 16-row
  // segments j=0,1; lane l -> row +(l>>2), ushort col (l&3)*8.
  // LDS lane offset (l>>2)*32 + (l&3)*8 == l*8 ushorts == l*16 bytes (linear).
  const int wrow = wid * 32;
  const int wl_r = lane >> 2;
  const int wl_c = (lane & 3) * 8;
  unsigned short* AhsF = &Ahs[0][0];
  unsigned short* AlsF = &Als[0][0];
  unsigned short* WhsF = &Whs[0][0];
  unsigned short* WlsF = &Wls[0][0];

  f32x4 acc[4][4];
#pragma unroll
  for (int i = 0; i < 4; ++i)
#pragma unroll
    for (int j = 0; j < 4; ++j) acc[i][j] = (f32x4){0.f, 0.f, 0.f, 0.f};

  for (int kt = 0; kt < Kd; kt += 32) {
    __syncthreads();   // previous tile fully consumed
#pragma unroll
    for (int j = 0; j < 2; ++j) {
      const size_t ga  = (size_t)(m0 + wrow + j*16 + wl_r) * Kd + kt + wl_c;
      const size_t gw  = (size_t)(r0 + wrow + j*16 + wl_r) * Kd + kt + wl_c;
      const int    lof = wid * 1024 + j * 512;
      gl_lds16(Ah_g + ga, AhsF + lof);
      gl_lds16(Al_g + ga, AlsF + lof);
      gl_lds16(Wh_g + gw, WhsF + lof);
      gl_lds16(Wl_g + gw, WlsF + lof);
    }
    __syncthreads();   // staging complete (compiler drains vmcnt)

    // ---- fragments + MFMA ----
    s16x8 fah[4], fal[4], fbh[4], fbl[4];
#pragma unroll
    for (int i = 0; i < 4; ++i) {
      const int row = wr * 64 + i * 16 + r16;
      fah[i] = *(const s16x8*)&Ahs[row][g * 8];
      fal[i] = *(const s16x8*)&Als[row][g * 8];
    }
#pragma unroll
    for (int j = 0; j < 4; ++j) {
      const int row = wc * 64 + j * 16 + r16;
      fbh[j] = *(const s16x8*)&Whs[row][g * 8];
      fbl[j] = *(const s16x8*)&Wls[row][g * 8];
    }
#pragma unroll
    for (int i = 0; i < 4; ++i) {
#pragma unroll
      for (int j = 0; j < 4; ++j) {
        acc[i][j] = __builtin_amdgcn_mfma_f32_16x16x32_bf16(fah[i], fbh[j], acc[i][j], 0, 0, 0);
        acc[i][j] = __builtin_amdgcn_mfma_f32_16x16x32_bf16(fah[i], fbl[j], acc[i][j], 0, 0, 0);
        acc[i][j] = __builtin_amdgcn_mfma_f32_16x16x32_bf16(fal[i], fbh[j], acc[i][j], 0, 0, 0);
      }
    }
  }

  // ---- epilogue (C/D frag: col = lane&15, row = (lane>>4)*4 + reg) ----
#pragma unroll
  for (int nj = 0; nj < 4; ++nj) {
    const int colb = r0 + wc * 64 + nj * 16;   // 16-aligned -> frag within one (tsel,h) block
    const float bj = bias[colb + r16];
    if constexpr (MODE == 0) {
      const int tsel = colb >> 10;
      const int h    = (colb & 1023) >> 6;
      const int d    = (colb & 63) + r16;
      float* dst = (tsel == 0) ? out0 : (tsel == 1) ? out1 : out2;
      const bool sig = (tsel < 2);
      float ssum = 0.f;
#pragma unroll
      for (int mi = 0; mi < 4; ++mi) {
#pragma unroll
        for (int rg = 0; rg < 4; ++rg) {
          const int m = m0 + wr * 64 + mi * 16 + g * 4 + rg;
          float xv = acc[mi][nj][rg] + bj;
          if (sig) { xv = sigmoid_f(xv); ssum += xv; }
          const int b = m >> 12, n = m & 4095;
          dst[((size_t)(b * Hc + h) * Nc + n) * Dc + d] = xv;
        }
      }
      if (sig) {
        // fused q_sum/k_sum: reduce over the 4 row-groups (lane bits 4,5)
        ssum += __shfl_xor(ssum, 16);
        ssum += __shfl_xor(ssum, 32);
        if (g == 0) {
          const int b = (m0 + wr * 64) >> 12;   // uniform within wave slice
          float* sdst = (tsel == 0) ? qsum_g : ksum_g;
          atomicAdd(&sdst[(b * Hc + h) * 64 + d], ssum);
        }
      }
    } else {
#pragma unroll
      for (int mi = 0; mi < 4; ++mi) {
#pragma unroll
        for (int rg = 0; rg < 4; ++rg) {
          const int m = m0 + wr * 64 + mi * 16 + g * 4 + rg;
          out0[(size_t)m * 1024 + colb + r16] = acc[mi][nj][rg] + bj;
        }
      }
    }
  }
}

// ---------------------------------------------------------------------------
// K3: si[n]=1/sum_d (q+e)(k_sum+e); so[n]=1/sum_d (k+e)(q_sum+e)
//     q_si_sum[d] += q[n,d]*si[n];  k_so_sum[d] += k[n,d]*so[n]
// ---------------------------------------------------------------------------
__global__ __launch_bounds__(256)
void siso_kernel(const float* __restrict__ qb, const float* __restrict__ kb,
                 const float* __restrict__ q_sum, const float* __restrict__ k_sum,
                 float* __restrict__ si, float* __restrict__ so,
                 float* __restrict__ q_si_sum, float* __restrict__ k_so_sum)
{
  const int bh = blockIdx.x, chunk = blockIdx.y;
  const int t = threadIdx.x, lane = t & 63, w = t >> 6;
  const float ksd = k_sum[bh*64 + lane] + EPSF;
  const float qsd = q_sum[bh*64 + lane] + EPSF;
  float kso_p = 0.f, qsi_p = 0.f;
  const size_t rowbase = (size_t)bh * Nc;
  for (int i = 0; i < 128; ++i) {
    const int n = chunk*512 + i*4 + w;
    const size_t off = (rowbase + n) * Dc + lane;
    const float qv = qb[off];
    const float kv = kb[off];
    float s1 = (qv + EPSF) * ksd;
    float s2 = (kv + EPSF) * qsd;
#pragma unroll
    for (int o = 32; o > 0; o >>= 1) {
      s1 += __shfl_xor(s1, o);
      s2 += __shfl_xor(s2, o);
    }
    const float si_n = 1.f / s1;
    const float so_n = 1.f / s2;
    if (lane == 0) { si[rowbase + n] = si_n; so[rowbase + n] = so_n; }
    qsi_p = __builtin_fmaf(qv, si_n, qsi_p);
    kso_p = __builtin_fmaf(kv, so_n, kso_p);
  }
  __shared__ float red[2][4][64];
  red[0][w][lane] = qsi_p; red[1][w][lane] = kso_p;
  __syncthreads();
  if (t < 64) {
    atomicAdd(&q_si_sum[bh*64 + t], red[0][0][t]+red[0][1][t]+red[0][2][t]+red[0][3][t]);
  } else if (t < 128) {
    const int l = t - 64;
    atomicAdd(&k_so_sum[bh*64 + l], red[1][0][l]+red[1][1][l]+red[1][2][l]+red[1][3][l]);
  }
}

// ---------------------------------------------------------------------------
// K4: conserved sink/source -> qscale (sa*si), sc_raw (exp), exp_sum
// ---------------------------------------------------------------------------
__global__ __launch_bounds__(256)
void conserved_kernel(const float* __restrict__ qb, const float* __restrict__ kb,
                      const float* __restrict__ q_si_sum, const float* __restrict__ k_so_sum,
                      const float* __restrict__ si,
                      float* __restrict__ qscale, float* __restrict__ sc_raw,
                      float* __restrict__ exp_sum)
{
  const int bh = blockIdx.x, chunk = blockIdx.y;
  const int t = threadIdx.x, lane = t & 63, w = t >> 6;
  const float ksod = k_so_sum[bh*64 + lane] + EPSF;
  const float qsid = q_si_sum[bh*64 + lane] + EPSF;
  float ep = 0.f;
  const size_t rowbase = (size_t)bh * Nc;
  for (int i = 0; i < 128; ++i) {
    const int n = chunk*512 + i*4 + w;
    const size_t off = (rowbase + n) * Dc + lane;
    const float qv = qb[off];
    const float kv = kb[off];
    float s1 = (qv + EPSF) * ksod;
    float s2 = (kv + EPSF) * qsid;
#pragma unroll
    for (int o = 32; o > 0; o >>= 1) {
      s1 += __shfl_xor(s1, o);
      s2 += __shfl_xor(s2, o);
    }
    const float sa = sigmoid_f(s1 + EPSF);
    float cs = s2 + EPSF;
    cs = fminf(fmaxf(cs, -1.f), 1.f);
    const float e = __expf(cs);
    if (lane == 0) {
      qscale[rowbase + n] = sa * si[rowbase + n];
      sc_raw[rowbase + n] = e;
      ep += e;
    }
  }
  __shared__ float red[4];
  if (lane == 0) red[w] = ep;
  __syncthreads();
  if (t == 0) atomicAdd(&exp_sum[bh], red[0]+red[1]+red[2]+red[3]);
}

// ---------------------------------------------------------------------------
// K6: kv[bh][d][m] = sum_n k[n,d] * v[n,m] * sc[n],  sc = sc_raw*N/exp_sum
// grid (64, 16): 1024 blocks (4/CU) for latency hiding; atomic partials.
// ---------------------------------------------------------------------------
__global__ __launch_bounds__(256)
void kv_kernel(const float* __restrict__ kb, const float* __restrict__ vb,
               const float* __restrict__ sc_raw, const float* __restrict__ exp_sum,
               float* __restrict__ kvout)
{
  const int bh = blockIdx.x, ch = blockIdx.y;
  const int t = threadIdx.x;
  const int m = t & 63, dg = t >> 6;
  const float scl = (float)Nc / exp_sum[bh];
  __shared__ float ks[64][64];
  __shared__ float vs[64][64];
  float acc[16];
#pragma unroll
  for (int i = 0; i < 16; ++i) acc[i] = 0.f;

  for (int c0 = ch*256; c0 < ch*256 + 256; c0 += 64) {
    __syncthreads();
#pragma unroll
    for (int j = 0; j < 4; ++j) {
      const int f = t + 256*j;
      const int row = f >> 4, cb = (f & 15) * 4;
      const size_t gidx = ((size_t)bh*Nc + c0 + row) * Dc + cb;
      *(float4*)&ks[row][cb] = *(const float4*)&kb[gidx];
      float4 vv = *(const float4*)&vb[gidx];
      const float s = sc_raw[(size_t)bh*Nc + c0 + row] * scl;
      vv.x *= s; vv.y *= s; vv.z *= s; vv.w *= s;
      *(float4*)&vs[row][cb] = vv;
    }
    __syncthreads();
#pragma unroll 8
    for (int n = 0; n < 64; ++n) {
      const float vv = vs[n][m];
#pragma unroll
      for (int dd = 0; dd < 4; ++dd) {
        float4 kk = *(const float4*)&ks[n][dg*16 + dd*4];
        acc[dd*4+0] = __builtin_fmaf(kk.x, vv, acc[dd*4+0]);
        acc[dd*4+1] = __builtin_fmaf(kk.y, vv, acc[dd*4+1]);
        acc[dd*4+2] = __builtin_fmaf(kk.z, vv, acc[dd*4+2]);
        acc[dd*4+3] = __builtin_fmaf(kk.w, vv, acc[dd*4+3]);
      }
    }
  }
#pragma unroll
  for (int dd = 0; dd < 16; ++dd)
    atomicAdd(&kvout[(size_t)bh*4096 + (size_t)(dg*16 + dd)*64 + m], acc[dd]);
}

// ---------------------------------------------------------------------------
// K7: attn[m][h*64+mm] = qscale[n] * sum_d q[n,d]*kv[d][mm] -> bf16 hi/lo
// ---------------------------------------------------------------------------
__global__ __launch_bounds__(256)
void out_kernel(const float* __restrict__ qb, const float* __restrict__ kvin,
                const float* __restrict__ qscale,
                unsigned short* __restrict__ attn_h, unsigned short* __restrict__ attn_l)
{
  const int bh = blockIdx.x, cy = blockIdx.y;
  const int t = threadIdx.x;
  const int c0 = cy * 64;
  __shared__ float kvs[64][68];
  __shared__ float qT[64][68];
  __shared__ float qsc[64];

#pragma unroll
  for (int j = 0; j < 4; ++j) {
    const int f = t + 256*j;
    const int d = f >> 4, cb = (f & 15) * 4;
    *(float4*)&kvs[d][cb] = *(const float4*)&kvin[(size_t)bh*4096 + (size_t)d*64 + cb];
  }
#pragma unroll
  for (int j = 0; j < 4; ++j) {
    const int f = t + 256*j;
    const int n = f >> 4, db = (f & 15) * 4;
    float4 qv = *(const float4*)&qb[((size_t)bh*Nc + c0 + n) * Dc + db];
    qT[db+0][n] = qv.x; qT[db+1][n] = qv.y; qT[db+2][n] = qv.z; qT[db+3][n] = qv.w;
  }
  if (t < 16) *(float4*)&qsc[t*4] = *(const float4*)&qscale[(size_t)bh*Nc + c0 + t*4];
  __syncthreads();

  const int ng = t & 15, mg = t >> 4;
  float acc[4][4];
#pragma unroll
  for (int i = 0; i < 4; ++i)
#pragma unroll
    for (int j = 0; j < 4; ++j) acc[i][j] = 0.f;

#pragma unroll 16
  for (int d = 0; d < 64; ++d) {
    float4 a = *(const float4*)&qT[d][ng*4];
    float4 b = *(const float4*)&kvs[d][mg*4];
    float av[4] = {a.x,a.y,a.z,a.w};
    float bv[4] = {b.x,b.y,b.z,b.w};
#pragma unroll
    for (int i = 0; i < 4; ++i)
#pragma unroll
      for (int j = 0; j < 4; ++j)
        acc[i][j] = __builtin_fmaf(av[i], bv[j], acc[i][j]);
  }

  const int b = bh >> 4, h = bh & 15;
#pragma unroll
  for (int i = 0; i < 4; ++i) {
    const int n = c0 + ng*4 + i;
    const float s = qsc[ng*4 + i];
    const size_t base = ((size_t)b * Nc + n) * 1024 + h * Dc + mg * 4;
    ushort4 hh, ll;
    float v0 = acc[i][0]*s, v1 = acc[i][1]*s, v2 = acc[i][2]*s, v3 = acc[i][3]*s;
    split_trunc(v0, hh.x, ll.x);
    split_trunc(v1, hh.y, ll.y);
    split_trunc(v2, hh.z, ll.z);
    split_trunc(v3, hh.w, ll.w);
    *(ushort4*)&attn_h[base] = hh;
    *(ushort4*)&attn_l[base] = ll;
  }
}

// ---------------------------------------------------------------------------
extern "C" void kernel_launch(void* const* d_in, const int* in_sizes, int n_in,
                              void* d_out, int out_size, void* d_ws, size_t ws_size,
                              hipStream_t stream)
{
  const float* x      = (const float*)d_in[0];
  const float* qkv_w  = (const float*)d_in[1];
  const float* qkv_b  = (const float*)d_in[2];
  const float* proj_w = (const float*)d_in[3];
  const float* proj_b = (const float*)d_in[4];
  float* out = (float*)d_out;
  float* ws  = (float*)d_ws;

  float* qb = ws;
  float* kb = ws + HEADSZ;
  float* vb = ws + 2*HEADSZ;
  // attn (bf16 hi/lo) aliases vb: v is dead after kv_kernel.
  unsigned short* attn_h = (unsigned short*)vb;
  unsigned short* attn_l = attn_h + HEADSZ;     // HEADSZ ushorts, = vb exactly

  float* sm      = ws + 3*HEADSZ;
  float* q_sum   = sm;                  // 4096
  float* k_sum   = sm + 4096;           // 4096
  float* q_si    = sm + 8192;           // 4096
  float* k_so    = sm + 12288;          // 4096
  float* exp_sum = sm + 16384;          // 64 (padded to 4096)
  float* si      = sm + 20480;          // 262144
  float* so      = si + 262144;
  float* qscale  = so + 262144;
  float* sc_raw  = qscale + 262144;
  float* kvbuf   = sc_raw + 262144;     // 262144

  unsigned short* Wh = (unsigned short*)(kvbuf + 262144);  // 3072*1024
  unsigned short* Wl = Wh + 3145728;
  unsigned short* Ph = Wl + 3145728;                       // 1024*1024
  unsigned short* Pl = Ph + 1048576;

  // x hi/lo bf16 live in d_out (67.1 MB == d_out size exactly); dead before
  // the final proj GEMM overwrites d_out.
  unsigned short* xh = (unsigned short*)d_out;
  unsigned short* xl = xh + 16777216;

  hipMemsetAsync(sm, 0, 20480 * sizeof(float), stream);
  hipMemsetAsync(kvbuf, 0, 262144 * sizeof(float), stream);

  // splits (memory-bound): x (16.7M), qkv_w (3.1M), proj_w (1.0M)
  split_kernel<<<16384, 256, 0, stream>>>(x, xh, xl, 4194304);
  split_kernel<<<3072, 256, 0, stream>>>(qkv_w, Wh, Wl, 786432);
  split_kernel<<<1024, 256, 0, stream>>>(proj_w, Ph, Pl, 262144);

  // QKV: (16384x1024) x (3072x1024)^T -> q,k,v (sigmoid on q,k; fused sums)
  gemm_mfma<0><<<dim3(128, 24), 256, 0, stream>>>(xh, xl, Wh, Wl, qkv_b,
                                                  qb, kb, vb, q_sum, k_sum);

  siso_kernel<<<dim3(64, 8), 256, 0, stream>>>(qb, kb, q_sum, k_sum, si, so, q_si, k_so);
  conserved_kernel<<<dim3(64, 8), 256, 0, stream>>>(qb, kb, q_si, k_so, si, qscale, sc_raw, exp_sum);
  kv_kernel<<<dim3(64, 16), 256, 0, stream>>>(kb, vb, sc_raw, exp_sum, kvbuf);
  out_kernel<<<dim3(64, 64), 256, 0, stream>>>(qb, kvbuf, qscale, attn_h, attn_l);

  // proj: (16384x1024 bf16 hi/lo) x (1024x1024)^T -> out
  gemm_mfma<1><<<dim3(128, 8), 256, 0, stream>>>(attn_h, attn_l, Ph, Pl, proj_b,
                                                 out, nullptr, nullptr, nullptr, nullptr);
}

// Round 7
// 704.854 us; speedup vs baseline: 1.3053x; 1.3053x over previous
//
#include <hip/hip_runtime.h>
#include <cstdint>
#include <cstddef>

#define EPSF 1e-6f

static constexpr int Bc  = 4;
static constexpr int Nc  = 4096;
static constexpr int Hc  = 16;
static constexpr int Dc  = 64;
static constexpr size_t HEADSZ = (size_t)64 * Nc * Dc;   // 16,777,216 floats
static constexpr int Kd  = 1024;

typedef __attribute__((ext_vector_type(8))) short     s16x8;
typedef __attribute__((ext_vector_type(4))) float     f32x4;

__device__ __forceinline__ float sigmoid_f(float x) {
  return 1.0f / (1.0f + __expf(-x));
}

// ---- bf16 helpers ---------------------------------------------------------
__device__ __forceinline__ unsigned short bf16_rne(float x) {
  unsigned int b = __float_as_uint(x);
  b += 0x7fffu + ((b >> 16) & 1u);
  return (unsigned short)(b >> 16);
}
__device__ __forceinline__ float bf16_to_f(unsigned short u) {
  return __uint_as_float(((unsigned int)u) << 16);
}
__device__ __forceinline__ void split_trunc(float x, unsigned short& h, unsigned short& l) {
  unsigned int b  = __float_as_uint(x);
  unsigned int hb = b & 0xffff0000u;
  h = (unsigned short)(hb >> 16);
  float res = x - __uint_as_float(hb);
  l = (unsigned short)(__float_as_uint(res) >> 16);
}

__device__ __forceinline__ void gl_lds16(const unsigned short* g, unsigned short* l) {
  __builtin_amdgcn_global_load_lds(
      (const __attribute__((address_space(1))) unsigned int*)(const void*)g,
      (__attribute__((address_space(3))) unsigned int*)(void*)l,
      16, 0, 0);
}

// ---------------------------------------------------------------------------
// fp32 -> (hi, lo) bf16 split, RNE both.  n4 = nelems/4.
// ---------------------------------------------------------------------------
__global__ __launch_bounds__(256)
void split_kernel(const float* __restrict__ in, unsigned short* __restrict__ hi,
                  unsigned short* __restrict__ lo, int n4)
{
  int i = blockIdx.x * 256 + threadIdx.x;
  if (i >= n4) return;
  float4 v = ((const float4*)in)[i];
  ushort4 h, l;
  h.x = bf16_rne(v.x); l.x = bf16_rne(v.x - bf16_to_f(h.x));
  h.y = bf16_rne(v.y); l.y = bf16_rne(v.y - bf16_to_f(h.y));
  h.z = bf16_rne(v.z); l.z = bf16_rne(v.z - bf16_to_f(h.z));
  h.w = bf16_rne(v.w); l.w = bf16_rne(v.w - bf16_to_f(h.w));
  ((ushort4*)hi)[i] = h;
  ((ushort4*)lo)[i] = l;
}

// ---------------------------------------------------------------------------
// bf16x3 MFMA GEMM (TN), 128x128x32 tile, 4 waves, gload_lds staging.
// L2 swizzle:
// MODE 0 (grid 3072): XCD owns by-triple (by = xcd*3 + idx%3), sweeps all
//   128 bx (bx = idx/3). W-panels (~1.5 MB) L2-resident; A stream phase-
//   shared across XCDs via L3. q/k/v scatter + sigmoid(q,k) + fused sums.
// MODE 1 (grid 1024): bx = xcd*16 + idx/8, by = idx%8; 8 sibling blocks per
//   A-panel consecutive on one XCD. Plain fp32 store.
// ---------------------------------------------------------------------------
template <int MODE>
__global__ __launch_bounds__(256)
void gemm_mfma(const unsigned short* __restrict__ Ah_g, const unsigned short* __restrict__ Al_g,
               const unsigned short* __restrict__ Wh_g, const unsigned short* __restrict__ Wl_g,
               const float* __restrict__ bias,
               float* __restrict__ out0, float* __restrict__ out1, float* __restrict__ out2,
               float* __restrict__ qsum_g, float* __restrict__ ksum_g)
{
  __shared__ unsigned short Ahs[128][32];
  __shared__ unsigned short Als[128][32];
  __shared__ unsigned short Whs[128][32];
  __shared__ unsigned short Wls[128][32];

  const int bid = blockIdx.x;
  const int xcd = bid & 7;
  const int idx = bid >> 3;      // [0, nwg/8)
  int bx, by;
  if constexpr (MODE == 0) {
    // nwg=3072, idx in [0,384): bx = idx/3 in [0,128), by = xcd*3 + idx%3 in [0,24)
    bx = idx / 3;
    by = xcd * 3 + idx % 3;
  } else {
    // nwg=1024, idx in [0,128): bx = xcd*16 + idx/8 in [0,128), by = idx%8
    bx = xcd * 16 + (idx >> 3);
    by = idx & 7;
  }

  const int t    = threadIdx.x;
  const int lane = t & 63;
  const int wid  = t >> 6;
  const int wr   = wid >> 1, wc = wid & 1;
  const int r16  = lane & 15, g = lane >> 4;
  const int m0   = bx * 128;
  const int r0   = by * 128;

  // DMA staging: wave wid rows [wid*32, +32), two 16-row segments.
  const int wrow = wid * 32;
  const int wl_r = lane >> 2;
  const int wl_c = (lane & 3) * 8;
  unsigned short* AhsF = &Ahs[0][0];
  unsigned short* AlsF = &Als[0][0];
  unsigned short* WhsF = &Whs[0][0];
  unsigned short* WlsF = &Wls[0][0];

  f32x4 acc[4][4];
#pragma unroll
  for (int i = 0; i < 4; ++i)
#pragma unroll
    for (int j = 0; j < 4; ++j) acc[i][j] = (f32x4){0.f, 0.f, 0.f, 0.f};

  for (int kt = 0; kt < Kd; kt += 32) {
    __syncthreads();
#pragma unroll
    for (int j = 0; j < 2; ++j) {
      const size_t ga  = (size_t)(m0 + wrow + j*16 + wl_r) * Kd + kt + wl_c;
      const size_t gw  = (size_t)(r0 + wrow + j*16 + wl_r) * Kd + kt + wl_c;
      const int    lof = wid * 1024 + j * 512;
      gl_lds16(Ah_g + ga, AhsF + lof);
      gl_lds16(Al_g + ga, AlsF + lof);
      gl_lds16(Wh_g + gw, WhsF + lof);
      gl_lds16(Wl_g + gw, WlsF + lof);
    }
    __syncthreads();

    s16x8 fah[4], fal[4], fbh[4], fbl[4];
#pragma unroll
    for (int i = 0; i < 4; ++i) {
      const int row = wr * 64 + i * 16 + r16;
      fah[i] = *(const s16x8*)&Ahs[row][g * 8];
      fal[i] = *(const s16x8*)&Als[row][g * 8];
    }
#pragma unroll
    for (int j = 0; j < 4; ++j) {
      const int row = wc * 64 + j * 16 + r16;
      fbh[j] = *(const s16x8*)&Whs[row][g * 8];
      fbl[j] = *(const s16x8*)&Wls[row][g * 8];
    }
#pragma unroll
    for (int i = 0; i < 4; ++i) {
#pragma unroll
      for (int j = 0; j < 4; ++j) {
        acc[i][j] = __builtin_amdgcn_mfma_f32_16x16x32_bf16(fah[i], fbh[j], acc[i][j], 0, 0, 0);
        acc[i][j] = __builtin_amdgcn_mfma_f32_16x16x32_bf16(fah[i], fbl[j], acc[i][j], 0, 0, 0);
        acc[i][j] = __builtin_amdgcn_mfma_f32_16x16x32_bf16(fal[i], fbh[j], acc[i][j], 0, 0, 0);
      }
    }
  }

  // ---- epilogue (C/D frag: col = lane&15, row = (lane>>4)*4 + reg) ----
#pragma unroll
  for (int nj = 0; nj < 4; ++nj) {
    const int colb = r0 + wc * 64 + nj * 16;
    const float bj = bias[colb + r16];
    if constexpr (MODE == 0) {
      const int tsel = colb >> 10;
      const int h    = (colb & 1023) >> 6;
      const int d    = (colb & 63) + r16;
      float* dst = (tsel == 0) ? out0 : (tsel == 1) ? out1 : out2;
      const bool sig = (tsel < 2);
      float ssum = 0.f;
#pragma unroll
      for (int mi = 0; mi < 4; ++mi) {
#pragma unroll
        for (int rg = 0; rg < 4; ++rg) {
          const int m = m0 + wr * 64 + mi * 16 + g * 4 + rg;
          float xv = acc[mi][nj][rg] + bj;
          if (sig) { xv = sigmoid_f(xv); ssum += xv; }
          const int b = m >> 12, n = m & 4095;
          dst[((size_t)(b * Hc + h) * Nc + n) * Dc + d] = xv;
        }
      }
      if (sig) {
        ssum += __shfl_xor(ssum, 16);
        ssum += __shfl_xor(ssum, 32);
        if (g == 0) {
          const int b = (m0 + wr * 64) >> 12;
          float* sdst = (tsel == 0) ? qsum_g : ksum_g;
          atomicAdd(&sdst[(b * Hc + h) * 64 + d], ssum);
        }
      }
    } else {
#pragma unroll
      for (int mi = 0; mi < 4; ++mi) {
#pragma unroll
        for (int rg = 0; rg < 4; ++rg) {
          const int m = m0 + wr * 64 + mi * 16 + g * 4 + rg;
          out0[(size_t)m * 1024 + colb + r16] = acc[mi][nj][rg] + bj;
        }
      }
    }
  }
}

// ---------------------------------------------------------------------------
// K3 v2: per row n: si=1/sum_d (q+e)(k_sum+e), so=1/sum_d (k+e)(q_sum+e);
// accumulate q_si_sum[d], k_so_sum[d]. Lane = (row-in-4, d-chunk-of-4).
// grid (64, 16), 256 thr: block = 256 rows; 4 rows/wave/iter, float4 loads.
// ---------------------------------------------------------------------------
__global__ __launch_bounds__(256)
void siso_kernel(const float* __restrict__ qb, const float* __restrict__ kb,
                 const float* __restrict__ q_sum, const float* __restrict__ k_sum,
                 float* __restrict__ si,
                 float* __restrict__ q_si_sum, float* __restrict__ k_so_sum)
{
  const int bh = blockIdx.x;
  const int t = threadIdx.x, lane = t & 63, w = t >> 6;
  const int c = lane & 15, r = lane >> 4;
  float4 ksd = *(const float4*)&k_sum[bh*64 + c*4];
  float4 qsd = *(const float4*)&q_sum[bh*64 + c*4];
  ksd.x += EPSF; ksd.y += EPSF; ksd.z += EPSF; ksd.w += EPSF;
  qsd.x += EPSF; qsd.y += EPSF; qsd.z += EPSF; qsd.w += EPSF;
  float4 qsi_p = {0,0,0,0}, kso_p = {0,0,0,0};
  const size_t rowbase = (size_t)bh * Nc;
  const int n00 = blockIdx.y * 256 + w * 64;
  for (int i = 0; i < 16; ++i) {
    const int n = n00 + i*4 + r;
    const size_t off = (rowbase + n) * Dc + c*4;
    float4 qv = *(const float4*)&qb[off];
    float4 kv = *(const float4*)&kb[off];
    float s1 = (qv.x+EPSF)*ksd.x + (qv.y+EPSF)*ksd.y + (qv.z+EPSF)*ksd.z + (qv.w+EPSF)*ksd.w;
    float s2 = (kv.x+EPSF)*qsd.x + (kv.y+EPSF)*qsd.y + (kv.z+EPSF)*qsd.z + (kv.w+EPSF)*qsd.w;
#pragma unroll
    for (int o = 1; o < 16; o <<= 1) {
      s1 += __shfl_xor(s1, o);
      s2 += __shfl_xor(s2, o);
    }
    const float si_n = 1.f / s1;
    const float so_n = 1.f / s2;
    if (c == 0) si[rowbase + n] = si_n;
    qsi_p.x = __builtin_fmaf(qv.x, si_n, qsi_p.x);
    qsi_p.y = __builtin_fmaf(qv.y, si_n, qsi_p.y);
    qsi_p.z = __builtin_fmaf(qv.z, si_n, qsi_p.z);
    qsi_p.w = __builtin_fmaf(qv.w, si_n, qsi_p.w);
    kso_p.x = __builtin_fmaf(kv.x, so_n, kso_p.x);
    kso_p.y = __builtin_fmaf(kv.y, so_n, kso_p.y);
    kso_p.z = __builtin_fmaf(kv.z, so_n, kso_p.z);
    kso_p.w = __builtin_fmaf(kv.w, so_n, kso_p.w);
  }
  // sum the 4 r-groups (lanes differing in bits 4,5)
#pragma unroll
  for (int o = 16; o < 64; o <<= 1) {
    qsi_p.x += __shfl_xor(qsi_p.x, o); qsi_p.y += __shfl_xor(qsi_p.y, o);
    qsi_p.z += __shfl_xor(qsi_p.z, o); qsi_p.w += __shfl_xor(qsi_p.w, o);
    kso_p.x += __shfl_xor(kso_p.x, o); kso_p.y += __shfl_xor(kso_p.y, o);
    kso_p.z += __shfl_xor(kso_p.z, o); kso_p.w += __shfl_xor(kso_p.w, o);
  }
  __shared__ float red[2][4][64];
  if (r == 0) {
    *(float4*)&red[0][w][c*4] = qsi_p;
    *(float4*)&red[1][w][c*4] = kso_p;
  }
  __syncthreads();
  if (t < 64) {
    atomicAdd(&q_si_sum[bh*64 + t], red[0][0][t]+red[0][1][t]+red[0][2][t]+red[0][3][t]);
  } else if (t < 128) {
    const int l = t - 64;
    atomicAdd(&k_so_sum[bh*64 + l], red[1][0][l]+red[1][1][l]+red[1][2][l]+red[1][3][l]);
  }
}

// ---------------------------------------------------------------------------
// K4 v2: conserved sink/source -> qscale (sa*si), sc_raw (exp), exp_sum
// Same lane layout as siso v2. grid (64,16), 256 thr.
// ---------------------------------------------------------------------------
__global__ __launch_bounds__(256)
void conserved_kernel(const float* __restrict__ qb, const float* __restrict__ kb,
                      const float* __restrict__ q_si_sum, const float* __restrict__ k_so_sum,
                      const float* __restrict__ si,
                      float* __restrict__ qscale, float* __restrict__ sc_raw,
                      float* __restrict__ exp_sum)
{
  const int bh = blockIdx.x;
  const int t = threadIdx.x, lane = t & 63, w = t >> 6;
  const int c = lane & 15, r = lane >> 4;
  float4 ksod = *(const float4*)&k_so_sum[bh*64 + c*4];
  float4 qsid = *(const float4*)&q_si_sum[bh*64 + c*4];
  ksod.x += EPSF; ksod.y += EPSF; ksod.z += EPSF; ksod.w += EPSF;
  qsid.x += EPSF; qsid.y += EPSF; qsid.z += EPSF; qsid.w += EPSF;
  float ep = 0.f;
  const size_t rowbase = (size_t)bh * Nc;
  const int n00 = blockIdx.y * 256 + w * 64;
  for (int i = 0; i < 16; ++i) {
    const int n = n00 + i*4 + r;
    const size_t off = (rowbase + n) * Dc + c*4;
    float4 qv = *(const float4*)&qb[off];
    float4 kv = *(const float4*)&kb[off];
    float s1 = (qv.x+EPSF)*ksod.x + (qv.y+EPSF)*ksod.y + (qv.z+EPSF)*ksod.z + (qv.w+EPSF)*ksod.w;
    float s2 = (kv.x+EPSF)*qsid.x + (kv.y+EPSF)*qsid.y + (kv.z+EPSF)*qsid.z + (kv.w+EPSF)*qsid.w;
#pragma unroll
    for (int o = 1; o < 16; o <<= 1) {
      s1 += __shfl_xor(s1, o);
      s2 += __shfl_xor(s2, o);
    }
    if (c == 0) {
      const float sa = sigmoid_f(s1 + EPSF);
      float cs = s2 + EPSF;
      cs = fminf(fmaxf(cs, -1.f), 1.f);
      const float e = __expf(cs);
      qscale[rowbase + n] = sa * si[rowbase + n];
      sc_raw[rowbase + n] = e;
      ep += e;
    }
  }
  // ep lives on lanes c==0 (lanes 0,16,32,48): xor 16/32 sums them
  ep += __shfl_xor(ep, 16);
  ep += __shfl_xor(ep, 32);
  __shared__ float red[4];
  if (lane == 0) red[w] = ep;
  __syncthreads();
  if (t == 0) atomicAdd(&exp_sum[bh], red[0]+red[1]+red[2]+red[3]);
}

// ---------------------------------------------------------------------------
// K6: kv[bh][d][m] = sum_n k[n,d] * v[n,m] * sc[n],  sc = sc_raw*N/exp_sum
// ---------------------------------------------------------------------------
__global__ __launch_bounds__(256)
void kv_kernel(const float* __restrict__ kb, const float* __restrict__ vb,
               const float* __restrict__ sc_raw, const float* __restrict__ exp_sum,
               float* __restrict__ kvout)
{
  const int bh = blockIdx.x, ch = blockIdx.y;
  const int t = threadIdx.x;
  const int m = t & 63, dg = t >> 6;
  const float scl = (float)Nc / exp_sum[bh];
  __shared__ float ks[64][64];
  __shared__ float vs[64][64];
  float acc[16];
#pragma unroll
  for (int i = 0; i < 16; ++i) acc[i] = 0.f;

  for (int c0 = ch*256; c0 < ch*256 + 256; c0 += 64) {
    __syncthreads();
#pragma unroll
    for (int j = 0; j < 4; ++j) {
      const int f = t + 256*j;
      const int row = f >> 4, cb = (f & 15) * 4;
      const size_t gidx = ((size_t)bh*Nc + c0 + row) * Dc + cb;
      *(float4*)&ks[row][cb] = *(const float4*)&kb[gidx];
      float4 vv = *(const float4*)&vb[gidx];
      const float s = sc_raw[(size_t)bh*Nc + c0 + row] * scl;
      vv.x *= s; vv.y *= s; vv.z *= s; vv.w *= s;
      *(float4*)&vs[row][cb] = vv;
    }
    __syncthreads();
#pragma unroll 8
    for (int n = 0; n < 64; ++n) {
      const float vv = vs[n][m];
#pragma unroll
      for (int dd = 0; dd < 4; ++dd) {
        float4 kk = *(const float4*)&ks[n][dg*16 + dd*4];
        acc[dd*4+0] = __builtin_fmaf(kk.x, vv, acc[dd*4+0]);
        acc[dd*4+1] = __builtin_fmaf(kk.y, vv, acc[dd*4+1]);
        acc[dd*4+2] = __builtin_fmaf(kk.z, vv, acc[dd*4+2]);
        acc[dd*4+3] = __builtin_fmaf(kk.w, vv, acc[dd*4+3]);
      }
    }
  }
#pragma unroll
  for (int dd = 0; dd < 16; ++dd)
    atomicAdd(&kvout[(size_t)bh*4096 + (size_t)(dg*16 + dd)*64 + m], acc[dd]);
}

// ---------------------------------------------------------------------------
// K7: attn[m][h*64+mm] = qscale[n] * sum_d q[n,d]*kv[d][mm] -> bf16 hi/lo
// ---------------------------------------------------------------------------
__global__ __launch_bounds__(256)
void out_kernel(const float* __restrict__ qb, const float* __restrict__ kvin,
                const float* __restrict__ qscale,
                unsigned short* __restrict__ attn_h, unsigned short* __restrict__ attn_l)
{
  const int bh = blockIdx.x, cy = blockIdx.y;
  const int t = threadIdx.x;
  const int c0 = cy * 64;
  __shared__ float kvs[64][68];
  __shared__ float qT[64][68];
  __shared__ float qsc[64];

#pragma unroll
  for (int j = 0; j < 4; ++j) {
    const int f = t + 256*j;
    const int d = f >> 4, cb = (f & 15) * 4;
    *(float4*)&kvs[d][cb] = *(const float4*)&kvin[(size_t)bh*4096 + (size_t)d*64 + cb];
  }
#pragma unroll
  for (int j = 0; j < 4; ++j) {
    const int f = t + 256*j;
    const int n = f >> 4, db = (f & 15) * 4;
    float4 qv = *(const float4*)&qb[((size_t)bh*Nc + c0 + n) * Dc + db];
    qT[db+0][n] = qv.x; qT[db+1][n] = qv.y; qT[db+2][n] = qv.z; qT[db+3][n] = qv.w;
  }
  if (t < 16) *(float4*)&qsc[t*4] = *(const float4*)&qscale[(size_t)bh*Nc + c0 + t*4];
  __syncthreads();

  const int ng = t & 15, mg = t >> 4;
  float acc[4][4];
#pragma unroll
  for (int i = 0; i < 4; ++i)
#pragma unroll
    for (int j = 0; j < 4; ++j) acc[i][j] = 0.f;

#pragma unroll 16
  for (int d = 0; d < 64; ++d) {
    float4 a = *(const float4*)&qT[d][ng*4];
    float4 b = *(const float4*)&kvs[d][mg*4];
    float av[4] = {a.x,a.y,a.z,a.w};
    float bv[4] = {b.x,b.y,b.z,b.w};
#pragma unroll
    for (int i = 0; i < 4; ++i)
#pragma unroll
      for (int j = 0; j < 4; ++j)
        acc[i][j] = __builtin_fmaf(av[i], bv[j], acc[i][j]);
  }

  const int b = bh >> 4, h = bh & 15;
#pragma unroll
  for (int i = 0; i < 4; ++i) {
    const int n = c0 + ng*4 + i;
    const float s = qsc[ng*4 + i];
    const size_t base = ((size_t)b * Nc + n) * 1024 + h * Dc + mg * 4;
    ushort4 hh, ll;
    float v0 = acc[i][0]*s, v1 = acc[i][1]*s, v2 = acc[i][2]*s, v3 = acc[i][3]*s;
    split_trunc(v0, hh.x, ll.x);
    split_trunc(v1, hh.y, ll.y);
    split_trunc(v2, hh.z, ll.z);
    split_trunc(v3, hh.w, ll.w);
    *(ushort4*)&attn_h[base] = hh;
    *(ushort4*)&attn_l[base] = ll;
  }
}

// ---------------------------------------------------------------------------
extern "C" void kernel_launch(void* const* d_in, const int* in_sizes, int n_in,
                              void* d_out, int out_size, void* d_ws, size_t ws_size,
                              hipStream_t stream)
{
  const float* x      = (const float*)d_in[0];
  const float* qkv_w  = (const float*)d_in[1];
  const float* qkv_b  = (const float*)d_in[2];
  const float* proj_w = (const float*)d_in[3];
  const float* proj_b = (const float*)d_in[4];
  float* out = (float*)d_out;
  float* ws  = (float*)d_ws;

  float* qb = ws;
  float* kb = ws + HEADSZ;
  float* vb = ws + 2*HEADSZ;
  unsigned short* attn_h = (unsigned short*)vb;   // aliases vb (v dead after kv_kernel)
  unsigned short* attn_l = attn_h + HEADSZ;

  float* sm      = ws + 3*HEADSZ;
  float* q_sum   = sm;
  float* k_sum   = sm + 4096;
  float* q_si    = sm + 8192;
  float* k_so    = sm + 12288;
  float* exp_sum = sm + 16384;
  float* si      = sm + 20480;          // 262144
  float* qscale  = si + 262144;
  float* sc_raw  = qscale + 262144;
  float* kvbuf   = sc_raw + 262144;     // 262144

  unsigned short* Wh = (unsigned short*)(kvbuf + 262144);  // 3072*1024
  unsigned short* Wl = Wh + 3145728;
  unsigned short* Ph = Wl + 3145728;                       // 1024*1024
  unsigned short* Pl = Ph + 1048576;

  // x hi/lo bf16 live in d_out (= 67.1 MB exactly); dead before proj GEMM.
  unsigned short* xh = (unsigned short*)d_out;
  unsigned short* xl = xh + 16777216;

  hipMemsetAsync(sm, 0, 20480 * sizeof(float), stream);
  hipMemsetAsync(kvbuf, 0, 262144 * sizeof(float), stream);

  split_kernel<<<16384, 256, 0, stream>>>(x, xh, xl, 4194304);
  split_kernel<<<3072, 256, 0, stream>>>(qkv_w, Wh, Wl, 786432);
  split_kernel<<<1024, 256, 0, stream>>>(proj_w, Ph, Pl, 262144);

  // QKV: (16384x1024) x (3072x1024)^T -> q,k,v (sigmoid q,k; fused sums)
  gemm_mfma<0><<<3072, 256, 0, stream>>>(xh, xl, Wh, Wl, qkv_b,
                                         qb, kb, vb, q_sum, k_sum);

  siso_kernel<<<dim3(64, 16), 256, 0, stream>>>(qb, kb, q_sum, k_sum, si, q_si, k_so);
  conserved_kernel<<<dim3(64, 16), 256, 0, stream>>>(qb, kb, q_si, k_so, si, qscale, sc_raw, exp_sum);
  kv_kernel<<<dim3(64, 16), 256, 0, stream>>>(kb, vb, sc_raw, exp_sum, kvbuf);
  out_kernel<<<dim3(64, 64), 256, 0, stream>>>(qb, kvbuf, qscale, attn_h, attn_l);

  // proj: (16384x1024 bf16 hi/lo) x (1024x1024)^T -> out
  gemm_mfma<1><<<1024, 256, 0, stream>>>(attn_h, attn_l, Ph, Pl, proj_b,
                                         out, nullptr, nullptr, nullptr, nullptr);
}

// Round 10
// 683.839 us; speedup vs baseline: 1.3455x; 1.0307x over previous
//
#include <hip/hip_runtime.h>
#include <cstdint>
#include <cstddef>

#define EPSF 1e-6f

static constexpr int Bc  = 4;
static constexpr int Nc  = 4096;
static constexpr int Hc  = 16;
static constexpr int Dc  = 64;
static constexpr size_t HEADSZ = (size_t)64 * Nc * Dc;   // 16,777,216 floats
static constexpr int Kd  = 1024;
static constexpr int BUFSH = 24576;   // ushorts per ring buffer (48 KB)

typedef __attribute__((ext_vector_type(8))) short     s16x8;
typedef __attribute__((ext_vector_type(4))) float     f32x4;

__device__ __forceinline__ float sigmoid_f(float x) {
  return 1.0f / (1.0f + __expf(-x));
}

// ---- bf16 helpers ---------------------------------------------------------
__device__ __forceinline__ unsigned short bf16_rne(float x) {
  unsigned int b = __float_as_uint(x);
  b += 0x7fffu + ((b >> 16) & 1u);
  return (unsigned short)(b >> 16);
}
__device__ __forceinline__ float bf16_to_f(unsigned short u) {
  return __uint_as_float(((unsigned int)u) << 16);
}
__device__ __forceinline__ void split_trunc(float x, unsigned short& h, unsigned short& l) {
  unsigned int b  = __float_as_uint(x);
  unsigned int hb = b & 0xffff0000u;
  h = (unsigned short)(hb >> 16);
  float res = x - __uint_as_float(hb);
  l = (unsigned short)(__float_as_uint(res) >> 16);
}

__device__ __forceinline__ void gl_lds16(const unsigned short* g, unsigned short* l) {
  __builtin_amdgcn_global_load_lds(
      (const __attribute__((address_space(1))) unsigned int*)(const void*)g,
      (__attribute__((address_space(3))) unsigned int*)(void*)l,
      16, 0, 0);
}

// ---------------------------------------------------------------------------
// fp32 -> (hi, lo) bf16 split, RNE both.  n4 = nelems/4.
// ---------------------------------------------------------------------------
__global__ __launch_bounds__(256)
void split_kernel(const float* __restrict__ in, unsigned short* __restrict__ hi,
                  unsigned short* __restrict__ lo, int n4)
{
  int i = blockIdx.x * 256 + threadIdx.x;
  if (i >= n4) return;
  float4 v = ((const float4*)in)[i];
  ushort4 h, l;
  h.x = bf16_rne(v.x); l.x = bf16_rne(v.x - bf16_to_f(h.x));
  h.y = bf16_rne(v.y); l.y = bf16_rne(v.y - bf16_to_f(h.y));
  h.z = bf16_rne(v.z); l.z = bf16_rne(v.z - bf16_to_f(h.z));
  h.w = bf16_rne(v.w); l.w = bf16_rne(v.w - bf16_to_f(h.w));
  ((ushort4*)hi)[i] = h;
  ((ushort4*)lo)[i] = l;
}

// ---------------------------------------------------------------------------
// Ring-pipeline bf16x3 MFMA GEMM (TN): BM=256, BN=128, BK=32, 512 thr = 8
// waves (4M x 2N, 64x64 each). 3-buffer LDS ring (3 x 48 KB), counted
// s_waitcnt vmcnt(6) + raw s_barrier once per K-step; stage of buf t+2
// issued before compute of buf t.
// Chunk-XOR swizzle (T2, rule-21 both-sides): slot s of row r holds global
// 16B-chunk s ^ sigma(r), sigma(r) = (r>>1)&3 (row bits 1-2; invariant under
// all staging/read base offsets, which are multiples of 8 rows). Staging
// swizzles the per-lane GLOBAL address (LDS dest stays linear, as gl_lds
// requires); fragment reads XOR the same bits. A 16-lane fragment read group
// then spreads over all 8 bank spans (2 lanes each, 2-way = free) vs 2 spans
// (8-way) unswizzled.
// Buffer layout (ushort offsets): Ah 0 (256x32), Al 8192, Wh 16384, Wl 20480.
// ---------------------------------------------------------------------------
__device__ __forceinline__ void gstage(unsigned short* __restrict__ dst,
                                       const unsigned short* __restrict__ Ah_g,
                                       const unsigned short* __restrict__ Al_g,
                                       const unsigned short* __restrict__ Wh_g,
                                       const unsigned short* __restrict__ Wl_g,
                                       int m0, int r0, int kt, int wid, int lane)
{
  const int lr = lane >> 2;
  const int sw = ((lane & 3) ^ ((lr >> 1) & 3)) * 8;  // pre-swizzled global chunk
  const size_t g0 = (size_t)(m0 + wid*32 + lr) * Kd + kt + sw;
  const size_t g1 = g0 + (size_t)16 * Kd;       // +16 rows: sigma unchanged
  unsigned short* d0 = dst + wid*1024;          // wave-uniform LDS base
  gl_lds16(Ah_g + g0, d0);
  gl_lds16(Ah_g + g1, d0 + 512);
  gl_lds16(Al_g + g0, d0 + 8192);
  gl_lds16(Al_g + g1, d0 + 8704);
  const size_t gw = (size_t)(r0 + wid*16 + lr) * Kd + kt + sw;
  unsigned short* d1 = dst + 16384 + wid*512;
  gl_lds16(Wh_g + gw, d1);
  gl_lds16(Wl_g + gw, d1 + 4096);
}

__device__ __forceinline__ void gstep(const unsigned short* __restrict__ base,
                                      int wr, int wc, int r16, int g,
                                      f32x4 (&acc)[4][4])
{
  const unsigned short* Ah_s = base;
  const unsigned short* Al_s = base + 8192;
  const unsigned short* Wh_s = base + 16384;
  const unsigned short* Wl_s = base + 20480;
  const int gsw = (g ^ ((r16 >> 1) & 3)) * 8;   // swizzled chunk on read
  s16x8 fbh[4], fbl[4];
#pragma unroll
  for (int j = 0; j < 4; ++j) {
    const int off = (wc*64 + j*16 + r16)*32 + gsw;
    fbh[j] = *(const s16x8*)&Wh_s[off];
    fbl[j] = *(const s16x8*)&Wl_s[off];
  }
#pragma unroll
  for (int ph = 0; ph < 2; ++ph) {
    s16x8 fah[2], fal[2];
#pragma unroll
    for (int ii = 0; ii < 2; ++ii) {
      const int off = (wr*64 + (ph*2+ii)*16 + r16)*32 + gsw;
      fah[ii] = *(const s16x8*)&Ah_s[off];
      fal[ii] = *(const s16x8*)&Al_s[off];
    }
    __builtin_amdgcn_s_setprio(1);
#pragma unroll
    for (int pr = 0; pr < 3; ++pr)
#pragma unroll
      for (int ii = 0; ii < 2; ++ii)
#pragma unroll
        for (int j = 0; j < 4; ++j)
          acc[ph*2+ii][j] = __builtin_amdgcn_mfma_f32_16x16x32_bf16(
              (pr == 2) ? fal[ii] : fah[ii],
              (pr == 1) ? fbl[j]  : fbh[j],
              acc[ph*2+ii][j], 0, 0, 0);
    __builtin_amdgcn_s_setprio(0);
  }
}

#define WAIT_BAR(N) do { \
  asm volatile("s_waitcnt vmcnt(" #N ")" ::: "memory"); \
  __builtin_amdgcn_s_barrier(); \
} while (0)

template <int MODE>
__global__ __launch_bounds__(512)
void gemm_mfma(const unsigned short* __restrict__ Ah_g, const unsigned short* __restrict__ Al_g,
               const unsigned short* __restrict__ Wh_g, const unsigned short* __restrict__ Wl_g,
               const float* __restrict__ bias,
               float* __restrict__ out0, float* __restrict__ out1, float* __restrict__ out2,
               float* __restrict__ qsum_g, float* __restrict__ ksum_g)
{
  __shared__ unsigned short lds[3 * BUFSH];   // 144 KB

  const int bid = blockIdx.x;
  const int xcd = bid & 7;
  const int idx = bid >> 3;
  int bx, by;
  if constexpr (MODE == 0) {
    // grid 1536: by = xcd*3 + idx%3 in [0,24), bx = idx/3 in [0,64)
    by = xcd * 3 + idx % 3;
    bx = idx / 3;
  } else {
    // grid 512: by = xcd in [0,8), bx = idx in [0,64)
    by = xcd;
    bx = idx;
  }

  const int t    = threadIdx.x;
  const int lane = t & 63;
  const int wid  = t >> 6;              // 0..7
  const int wr   = wid >> 1, wc = wid & 1;
  const int r16  = lane & 15, g = lane >> 4;
  const int m0   = bx * 256;
  const int r0   = by * 128;

  f32x4 acc[4][4];
#pragma unroll
  for (int i = 0; i < 4; ++i)
#pragma unroll
    for (int j = 0; j < 4; ++j) acc[i][j] = (f32x4){0.f, 0.f, 0.f, 0.f};

  unsigned short* L = &lds[0];

  // prologue: stage buf0 (kt=0) and buf1 (kt=32); wait buf0 ready
  gstage(L,          Ah_g, Al_g, Wh_g, Wl_g, m0, r0, 0,  wid, lane);
  gstage(L + BUFSH,  Ah_g, Al_g, Wh_g, Wl_g, m0, r0, 32, wid, lane);
  WAIT_BAR(6);

  // steady state: steps 0..29 (3-unrolled); stage t+2, compute t, wait t+1
  for (int tt = 0; tt < 30; tt += 3) {
    const int kb = tt * 32;
    gstage(L + 2*BUFSH, Ah_g, Al_g, Wh_g, Wl_g, m0, r0, kb + 64,  wid, lane);
    gstep(L,           wr, wc, r16, g, acc);
    WAIT_BAR(6);
    gstage(L,           Ah_g, Al_g, Wh_g, Wl_g, m0, r0, kb + 96,  wid, lane);
    gstep(L + BUFSH,   wr, wc, r16, g, acc);
    WAIT_BAR(6);
    gstage(L + BUFSH,   Ah_g, Al_g, Wh_g, Wl_g, m0, r0, kb + 128, wid, lane);
    gstep(L + 2*BUFSH, wr, wc, r16, g, acc);
    WAIT_BAR(6);
  }
  // steps 30, 31: drain
  gstep(L, wr, wc, r16, g, acc);
  WAIT_BAR(0);
  gstep(L + BUFSH, wr, wc, r16, g, acc);

  // ---- epilogue (C/D frag: col = lane&15, row = (lane>>4)*4 + reg) ----
#pragma unroll
  for (int nj = 0; nj < 4; ++nj) {
    const int colb = r0 + wc * 64 + nj * 16;
    const float bj = bias[colb + r16];
    if constexpr (MODE == 0) {
      const int tsel = colb >> 10;
      const int h    = (colb & 1023) >> 6;
      const int d    = (colb & 63) + r16;
      float* dst = (tsel == 0) ? out0 : (tsel == 1) ? out1 : out2;
      const bool sig = (tsel < 2);
      float ssum = 0.f;
#pragma unroll
      for (int mi = 0; mi < 4; ++mi) {
#pragma unroll
        for (int rg = 0; rg < 4; ++rg) {
          const int m = m0 + wr * 64 + mi * 16 + g * 4 + rg;
          float xv = acc[mi][nj][rg] + bj;
          if (sig) { xv = sigmoid_f(xv); ssum += xv; }
          const int b = m >> 12, n = m & 4095;
          dst[((size_t)(b * Hc + h) * Nc + n) * Dc + d] = xv;
        }
      }
      if (sig) {
        ssum += __shfl_xor(ssum, 16);
        ssum += __shfl_xor(ssum, 32);
        if (g == 0) {
          const int b = (m0 + wr * 64) >> 12;   // 64-row wave slice stays in one batch
          float* sdst = (tsel == 0) ? qsum_g : ksum_g;
          atomicAdd(&sdst[(b * Hc + h) * 64 + d], ssum);
        }
      }
    } else {
#pragma unroll
      for (int mi = 0; mi < 4; ++mi) {
#pragma unroll
        for (int rg = 0; rg < 4; ++rg) {
          const int m = m0 + wr * 64 + mi * 16 + g * 4 + rg;
          out0[(size_t)m * 1024 + colb + r16] = acc[mi][nj][rg] + bj;
        }
      }
    }
  }
}

// ---------------------------------------------------------------------------
// K3 v2: per row n: si=1/sum_d (q+e)(k_sum+e), so=1/sum_d (k+e)(q_sum+e);
// accumulate q_si_sum[d], k_so_sum[d]. Lane = (row-in-4, d-chunk-of-4).
// ---------------------------------------------------------------------------
__global__ __launch_bounds__(256)
void siso_kernel(const float* __restrict__ qb, const float* __restrict__ kb,
                 const float* __restrict__ q_sum, const float* __restrict__ k_sum,
                 float* __restrict__ si,
                 float* __restrict__ q_si_sum, float* __restrict__ k_so_sum)
{
  const int bh = blockIdx.x;
  const int t = threadIdx.x, lane = t & 63, w = t >> 6;
  const int c = lane & 15, r = lane >> 4;
  float4 ksd = *(const float4*)&k_sum[bh*64 + c*4];
  float4 qsd = *(const float4*)&q_sum[bh*64 + c*4];
  ksd.x += EPSF; ksd.y += EPSF; ksd.z += EPSF; ksd.w += EPSF;
  qsd.x += EPSF; qsd.y += EPSF; qsd.z += EPSF; qsd.w += EPSF;
  float4 qsi_p = {0,0,0,0}, kso_p = {0,0,0,0};
  const size_t rowbase = (size_t)bh * Nc;
  const int n00 = blockIdx.y * 256 + w * 64;
  for (int i = 0; i < 16; ++i) {
    const int n = n00 + i*4 + r;
    const size_t off = (rowbase + n) * Dc + c*4;
    float4 qv = *(const float4*)&qb[off];
    float4 kv = *(const float4*)&kb[off];
    float s1 = (qv.x+EPSF)*ksd.x + (qv.y+EPSF)*ksd.y + (qv.z+EPSF)*ksd.z + (qv.w+EPSF)*ksd.w;
    float s2 = (kv.x+EPSF)*qsd.x + (kv.y+EPSF)*qsd.y + (kv.z+EPSF)*qsd.z + (kv.w+EPSF)*qsd.w;
#pragma unroll
    for (int o = 1; o < 16; o <<= 1) {
      s1 += __shfl_xor(s1, o);
      s2 += __shfl_xor(s2, o);
    }
    const float si_n = 1.f / s1;
    const float so_n = 1.f / s2;
    if (c == 0) si[rowbase + n] = si_n;
    qsi_p.x = __builtin_fmaf(qv.x, si_n, qsi_p.x);
    qsi_p.y = __builtin_fmaf(qv.y, si_n, qsi_p.y);
    qsi_p.z = __builtin_fmaf(qv.z, si_n, qsi_p.z);
    qsi_p.w = __builtin_fmaf(qv.w, si_n, qsi_p.w);
    kso_p.x = __builtin_fmaf(kv.x, so_n, kso_p.x);
    kso_p.y = __builtin_fmaf(kv.y, so_n, kso_p.y);
    kso_p.z = __builtin_fmaf(kv.z, so_n, kso_p.z);
    kso_p.w = __builtin_fmaf(kv.w, so_n, kso_p.w);
  }
#pragma unroll
  for (int o = 16; o < 64; o <<= 1) {
    qsi_p.x += __shfl_xor(qsi_p.x, o); qsi_p.y += __shfl_xor(qsi_p.y, o);
    qsi_p.z += __shfl_xor(qsi_p.z, o); qsi_p.w += __shfl_xor(qsi_p.w, o);
    kso_p.x += __shfl_xor(kso_p.x, o); kso_p.y += __shfl_xor(kso_p.y, o);
    kso_p.z += __shfl_xor(kso_p.z, o); kso_p.w += __shfl_xor(kso_p.w, o);
  }
  __shared__ float red[2][4][64];
  if (r == 0) {
    *(float4*)&red[0][w][c*4] = qsi_p;
    *(float4*)&red[1][w][c*4] = kso_p;
  }
  __syncthreads();
  if (t < 64) {
    atomicAdd(&q_si_sum[bh*64 + t], red[0][0][t]+red[0][1][t]+red[0][2][t]+red[0][3][t]);
  } else if (t < 128) {
    const int l = t - 64;
    atomicAdd(&k_so_sum[bh*64 + l], red[1][0][l]+red[1][1][l]+red[1][2][l]+red[1][3][l]);
  }
}

// ---------------------------------------------------------------------------
// K4 v2: conserved sink/source -> qscale (sa*si), sc_raw (exp), exp_sum
// ---------------------------------------------------------------------------
__global__ __launch_bounds__(256)
void conserved_kernel(const float* __restrict__ qb, const float* __restrict__ kb,
                      const float* __restrict__ q_si_sum, const float* __restrict__ k_so_sum,
                      const float* __restrict__ si,
                      float* __restrict__ qscale, float* __restrict__ sc_raw,
                      float* __restrict__ exp_sum)
{
  const int bh = blockIdx.x;
  const int t = threadIdx.x, lane = t & 63, w = t >> 6;
  const int c = lane & 15, r = lane >> 4;
  float4 ksod = *(const float4*)&k_so_sum[bh*64 + c*4];
  float4 qsid = *(const float4*)&q_si_sum[bh*64 + c*4];
  ksod.x += EPSF; ksod.y += EPSF; ksod.z += EPSF; ksod.w += EPSF;
  qsid.x += EPSF; qsid.y += EPSF; qsid.z += EPSF; qsid.w += EPSF;
  float ep = 0.f;
  const size_t rowbase = (size_t)bh * Nc;
  const int n00 = blockIdx.y * 256 + w * 64;
  for (int i = 0; i < 16; ++i) {
    const int n = n00 + i*4 + r;
    const size_t off = (rowbase + n) * Dc + c*4;
    float4 qv = *(const float4*)&qb[off];
    float4 kv = *(const float4*)&kb[off];
    float s1 = (qv.x+EPSF)*ksod.x + (qv.y+EPSF)*ksod.y + (qv.z+EPSF)*ksod.z + (qv.w+EPSF)*ksod.w;
    float s2 = (kv.x+EPSF)*qsid.x + (kv.y+EPSF)*qsid.y + (kv.z+EPSF)*qsid.z + (kv.w+EPSF)*qsid.w;
#pragma unroll
    for (int o = 1; o < 16; o <<= 1) {
      s1 += __shfl_xor(s1, o);
      s2 += __shfl_xor(s2, o);
    }
    if (c == 0) {
      const float sa = sigmoid_f(s1 + EPSF);
      float cs = s2 + EPSF;
      cs = fminf(fmaxf(cs, -1.f), 1.f);
      const float e = __expf(cs);
      qscale[rowbase + n] = sa * si[rowbase + n];
      sc_raw[rowbase + n] = e;
      ep += e;
    }
  }
  ep += __shfl_xor(ep, 16);
  ep += __shfl_xor(ep, 32);
  __shared__ float red[4];
  if (lane == 0) red[w] = ep;
  __syncthreads();
  if (t == 0) atomicAdd(&exp_sum[bh], red[0]+red[1]+red[2]+red[3]);
}

// ---------------------------------------------------------------------------
// K6: kv[bh][d][m] = sum_n k[n,d] * v[n,m] * sc[n],  sc = sc_raw*N/exp_sum
// ---------------------------------------------------------------------------
__global__ __launch_bounds__(256)
void kv_kernel(const float* __restrict__ kb, const float* __restrict__ vb,
               const float* __restrict__ sc_raw, const float* __restrict__ exp_sum,
               float* __restrict__ kvout)
{
  const int bh = blockIdx.x, ch = blockIdx.y;
  const int t = threadIdx.x;
  const int m = t & 63, dg = t >> 6;
  const float scl = (float)Nc / exp_sum[bh];
  __shared__ float ks[64][64];
  __shared__ float vs[64][64];
  float acc[16];
#pragma unroll
  for (int i = 0; i < 16; ++i) acc[i] = 0.f;

  for (int c0 = ch*256; c0 < ch*256 + 256; c0 += 64) {
    __syncthreads();
#pragma unroll
    for (int j = 0; j < 4; ++j) {
      const int f = t + 256*j;
      const int row = f >> 4, cb = (f & 15) * 4;
      const size_t gidx = ((size_t)bh*Nc + c0 + row) * Dc + cb;
      *(float4*)&ks[row][cb] = *(const float4*)&kb[gidx];
      float4 vv = *(const float4*)&vb[gidx];
      const float s = sc_raw[(size_t)bh*Nc + c0 + row] * scl;
      vv.x *= s; vv.y *= s; vv.z *= s; vv.w *= s;
      *(float4*)&vs[row][cb] = vv;
    }
    __syncthreads();
#pragma unroll 8
    for (int n = 0; n < 64; ++n) {
      const float vv = vs[n][m];
#pragma unroll
      for (int dd = 0; dd < 4; ++dd) {
        float4 kk = *(const float4*)&ks[n][dg*16 + dd*4];
        acc[dd*4+0] = __builtin_fmaf(kk.x, vv, acc[dd*4+0]);
        acc[dd*4+1] = __builtin_fmaf(kk.y, vv, acc[dd*4+1]);
        acc[dd*4+2] = __builtin_fmaf(kk.z, vv, acc[dd*4+2]);
        acc[dd*4+3] = __builtin_fmaf(kk.w, vv, acc[dd*4+3]);
      }
    }
  }
#pragma unroll
  for (int dd = 0; dd < 16; ++dd)
    atomicAdd(&kvout[(size_t)bh*4096 + (size_t)(dg*16 + dd)*64 + m], acc[dd]);
}

// ---------------------------------------------------------------------------
// K7: attn[m][h*64+mm] = qscale[n] * sum_d q[n,d]*kv[d][mm] -> bf16 hi/lo
// ---------------------------------------------------------------------------
__global__ __launch_bounds__(256)
void out_kernel(const float* __restrict__ qb, const float* __restrict__ kvin,
                const float* __restrict__ qscale,
                unsigned short* __restrict__ attn_h, unsigned short* __restrict__ attn_l)
{
  const int bh = blockIdx.x, cy = blockIdx.y;
  const int t = threadIdx.x;
  const int c0 = cy * 64;
  __shared__ float kvs[64][68];
  __shared__ float qT[64][68];
  __shared__ float qsc[64];

#pragma unroll
  for (int j = 0; j < 4; ++j) {
    const int f = t + 256*j;
    const int d = f >> 4, cb = (f & 15) * 4;
    *(float4*)&kvs[d][cb] = *(const float4*)&kvin[(size_t)bh*4096 + (size_t)d*64 + cb];
  }
#pragma unroll
  for (int j = 0; j < 4; ++j) {
    const int f = t + 256*j;
    const int n = f >> 4, db = (f & 15) * 4;
    float4 qv = *(const float4*)&qb[((size_t)bh*Nc + c0 + n) * Dc + db];
    qT[db+0][n] = qv.x; qT[db+1][n] = qv.y; qT[db+2][n] = qv.z; qT[db+3][n] = qv.w;
  }
  if (t < 16) *(float4*)&qsc[t*4] = *(const float4*)&qscale[(size_t)bh*Nc + c0 + t*4];
  __syncthreads();

  const int ng = t & 15, mg = t >> 4;
  float acc[4][4];
#pragma unroll
  for (int i = 0; i < 4; ++i)
#pragma unroll
    for (int j = 0; j < 4; ++j) acc[i][j] = 0.f;

#pragma unroll 16
  for (int d = 0; d < 64; ++d) {
    float4 a = *(const float4*)&qT[d][ng*4];
    float4 b = *(const float4*)&kvs[d][mg*4];
    float av[4] = {a.x,a.y,a.z,a.w};
    float bv[4] = {b.x,b.y,b.z,b.w};
#pragma unroll
    for (int i = 0; i < 4; ++i)
#pragma unroll
      for (int j = 0; j < 4; ++j)
        acc[i][j] = __builtin_fmaf(av[i], bv[j], acc[i][j]);
  }

  const int b = bh >> 4, h = bh & 15;
#pragma unroll
  for (int i = 0; i < 4; ++i) {
    const int n = c0 + ng*4 + i;
    const float s = qsc[ng*4 + i];
    const size_t base = ((size_t)b * Nc + n) * 1024 + h * Dc + mg * 4;
    ushort4 hh, ll;
    float v0 = acc[i][0]*s, v1 = acc[i][1]*s, v2 = acc[i][2]*s, v3 = acc[i][3]*s;
    split_trunc(v0, hh.x, ll.x);
    split_trunc(v1, hh.y, ll.y);
    split_trunc(v2, hh.z, ll.z);
    split_trunc(v3, hh.w, ll.w);
    *(ushort4*)&attn_h[base] = hh;
    *(ushort4*)&attn_l[base] = ll;
  }
}

// ---------------------------------------------------------------------------
extern "C" void kernel_launch(void* const* d_in, const int* in_sizes, int n_in,
                              void* d_out, int out_size, void* d_ws, size_t ws_size,
                              hipStream_t stream)
{
  const float* x      = (const float*)d_in[0];
  const float* qkv_w  = (const float*)d_in[1];
  const float* qkv_b  = (const float*)d_in[2];
  const float* proj_w = (const float*)d_in[3];
  const float* proj_b = (const float*)d_in[4];
  float* out = (float*)d_out;
  float* ws  = (float*)d_ws;

  float* qb = ws;
  float* kb = ws + HEADSZ;
  float* vb = ws + 2*HEADSZ;
  unsigned short* attn_h = (unsigned short*)vb;   // aliases vb (v dead after kv_kernel)
  unsigned short* attn_l = attn_h + HEADSZ;

  float* sm      = ws + 3*HEADSZ;
  float* q_sum   = sm;
  float* k_sum   = sm + 4096;
  float* q_si    = sm + 8192;
  float* k_so    = sm + 12288;
  float* exp_sum = sm + 16384;
  float* si      = sm + 20480;          // 262144
  float* qscale  = si + 262144;
  float* sc_raw  = qscale + 262144;
  float* kvbuf   = sc_raw + 262144;     // 262144

  unsigned short* Wh = (unsigned short*)(kvbuf + 262144);  // 3072*1024
  unsigned short* Wl = Wh + 3145728;
  unsigned short* Ph = Wl + 3145728;                       // 1024*1024
  unsigned short* Pl = Ph + 1048576;

  // x hi/lo bf16 live in d_out (= 67.1 MB exactly); dead before proj GEMM.
  unsigned short* xh = (unsigned short*)d_out;
  unsigned short* xl = xh + 16777216;

  hipMemsetAsync(sm, 0, 20480 * sizeof(float), stream);
  hipMemsetAsync(kvbuf, 0, 262144 * sizeof(float), stream);

  split_kernel<<<16384, 256, 0, stream>>>(x, xh, xl, 4194304);
  split_kernel<<<3072, 256, 0, stream>>>(qkv_w, Wh, Wl, 786432);
  split_kernel<<<1024, 256, 0, stream>>>(proj_w, Ph, Pl, 262144);

  // QKV: (16384x1024) x (3072x1024)^T -> q,k,v (sigmoid q,k; fused sums)
  gemm_mfma<0><<<1536, 512, 0, stream>>>(xh, xl, Wh, Wl, qkv_b,
                                         qb, kb, vb, q_sum, k_sum);

  siso_kernel<<<dim3(64, 16), 256, 0, stream>>>(qb, kb, q_sum, k_sum, si, q_si, k_so);
  conserved_kernel<<<dim3(64, 16), 256, 0, stream>>>(qb, kb, q_si, k_so, si, qscale, sc_raw, exp_sum);
  kv_kernel<<<dim3(64, 16), 256, 0, stream>>>(kb, vb, sc_raw, exp_sum, kvbuf);
  out_kernel<<<dim3(64, 64), 256, 0, stream>>>(qb, kvbuf, qscale, attn_h, attn_l);

  // proj: (16384x1024 bf16 hi/lo) x (1024x1024)^T -> out
  gemm_mfma<1><<<512, 512, 0, stream>>>(attn_h, attn_l, Ph, Pl, proj_b,
                                        out, nullptr, nullptr, nullptr, nullptr);
}